// Round 1
// baseline (127.523 us; speedup 1.0000x reference)
//
#include <hip/hip_runtime.h>
#include <hip/hip_bf16.h>

// SubjectLayers: out[b,t,o] = sum_i x[b,t,i] * w[sid[b],i,o] + bias[sid[b],o]
// B=256 T=512 IN=256 OUT=256 S=128, all fp32 in/out.
// Strategy: pre-pass transposes+converts weights to bf16 [S][OUT][IN] in d_ws,
// then a 128x128-tile bf16-MFMA GEMM (fused f32->bf16 convert on x staging).

#define B_DIM 256
#define T_DIM 512
#define IN_DIM 256
#define OUT_DIM 256
#define S_DIM 128

typedef __attribute__((ext_vector_type(4))) float f32x4;
typedef __attribute__((ext_vector_type(8))) short s16x8;
typedef __attribute__((ext_vector_type(8))) unsigned short u16x8;
typedef __attribute__((ext_vector_type(4))) unsigned short u16x4;

static __device__ __forceinline__ unsigned short f2bf(float f) {
  __hip_bfloat16 h = __float2bfloat16(f);
  return __builtin_bit_cast(unsigned short, h);
}

// Pre-pass: wT[s][o][i] = bf16(w[s][i][o]). 64x64 tiles via LDS.
__global__ __launch_bounds__(256) void wt_transpose(const float* __restrict__ w,
                                                    unsigned short* __restrict__ wT) {
  __shared__ float tile[64][65];
  int bid = blockIdx.x;
  int s = bid >> 4, ti = (bid >> 2) & 3, to = bid & 3;
  const float* wp = w + (size_t)s * IN_DIM * OUT_DIM;
  unsigned short* op = wT + (size_t)s * IN_DIM * OUT_DIM;
  int t = threadIdx.x;
  int rr = t >> 6, cc = t & 63;
#pragma unroll
  for (int p = 0; p < 16; ++p) {
    tile[p * 4 + rr][cc] = wp[(size_t)(ti * 64 + p * 4 + rr) * OUT_DIM + to * 64 + cc];
  }
  __syncthreads();
  int orr = t >> 4, i4 = (t & 15) * 4;
#pragma unroll
  for (int p = 0; p < 4; ++p) {
    int ol = p * 16 + orr;  // o within tile
    u16x4 v;
    v[0] = f2bf(tile[i4 + 0][ol]);
    v[1] = f2bf(tile[i4 + 1][ol]);
    v[2] = f2bf(tile[i4 + 2][ol]);
    v[3] = f2bf(tile[i4 + 3][ol]);
    *(u16x4*)(op + (size_t)(to * 64 + ol) * IN_DIM + ti * 64 + i4) = v;
  }
}

// GEMM: per block batch b, 128 T-rows, 128 OUT-cols. 4 waves, wave tile 64x64.
// BK=64, K=256 -> 4 steps. LDS bf16 [row][k] with XOR swizzle (^(row&7)<<3 in ushorts).
__global__ __launch_bounds__(256, 2) void subj_gemm(
    const float* __restrict__ x, const int* __restrict__ sid,
    const unsigned short* __restrict__ wT, const float* __restrict__ bias,
    float* __restrict__ out) {
  __shared__ __align__(16) unsigned short lA[128 * 64];
  __shared__ __align__(16) unsigned short lB[128 * 64];

  // pair-swizzle so the two nt-tiles of one (batch,mt) share an XCD (L2 reuse of x)
  unsigned wg = blockIdx.x;
  unsigned bid = (wg & ~15u) | ((wg & 7u) << 1) | ((wg >> 3) & 1u);
  int batch = bid >> 3;
  int mt = (bid >> 1) & 3;
  int nt = bid & 1;
  int s = sid[batch];

  const float* xA = x + ((size_t)batch * T_DIM + mt * 128) * IN_DIM;
  const unsigned short* wB =
      wT + (size_t)s * IN_DIM * OUT_DIM + (size_t)(nt * 128) * IN_DIM;

  int t = threadIdx.x;
  int l = t & 63, wv = t >> 6;
  int wm = (wv >> 1) * 64, wn = (wv & 1) * 64;
  int fr = l & 15;           // frag row/col
  int kq = (l >> 4) * 8;     // k offset within 32
  int r0 = (l >> 4) * 4;     // C/D row group

  f32x4 acc[4][4];
#pragma unroll
  for (int i = 0; i < 4; ++i)
#pragma unroll
    for (int j = 0; j < 4; ++j) acc[i][j] = (f32x4){0.f, 0.f, 0.f, 0.f};

  for (int kt = 0; kt < 4; ++kt) {
    int k0 = kt * 64;
    __syncthreads();
    // stage A: 128x64 f32 -> bf16, 8 float4 per thread, coalesced
#pragma unroll
    for (int it = 0; it < 8; ++it) {
      int f = it * 256 + t;
      int row = f >> 4;
      int kc = (f & 15) << 2;
      float4 v = *(const float4*)(xA + (size_t)row * IN_DIM + k0 + kc);
      u16x4 h;
      h[0] = f2bf(v.x); h[1] = f2bf(v.y); h[2] = f2bf(v.z); h[3] = f2bf(v.w);
      int idx = ((row << 6) | kc) ^ ((row & 7) << 3);
      *(u16x4*)(lA + idx) = h;
    }
    // stage B: 128x64 bf16, 4x16B per thread, coalesced
#pragma unroll
    for (int it = 0; it < 4; ++it) {
      int c = it * 256 + t;
      int n = c >> 3;
      int kc = (c & 7) << 3;
      u16x8 v = *(const u16x8*)(wB + (size_t)n * IN_DIM + k0 + kc);
      int idx = ((n << 6) | kc) ^ ((n & 7) << 3);
      *(u16x8*)(lB + idx) = v;
    }
    __syncthreads();
    // compute: 2 k-subtiles of 32, 16 MFMA each
#pragma unroll
    for (int ks = 0; ks < 2; ++ks) {
      int kk = ks * 32 + kq;
      s16x8 af[4], bf[4];
#pragma unroll
      for (int fm = 0; fm < 4; ++fm) {
        int row = wm + fm * 16 + fr;
        int idx = ((row << 6) | kk) ^ ((row & 7) << 3);
        af[fm] = *(const s16x8*)(lA + idx);
      }
#pragma unroll
      for (int fn = 0; fn < 4; ++fn) {
        int row = wn + fn * 16 + fr;
        int idx = ((row << 6) | kk) ^ ((row & 7) << 3);
        bf[fn] = *(const s16x8*)(lB + idx);
      }
#pragma unroll
      for (int fm = 0; fm < 4; ++fm)
#pragma unroll
        for (int fn = 0; fn < 4; ++fn)
          acc[fm][fn] = __builtin_amdgcn_mfma_f32_16x16x32_bf16(
              af[fm], bf[fn], acc[fm][fn], 0, 0, 0);
    }
  }

  // epilogue: add bias, store (16-lane groups write 64B contiguous)
  const float* bp = bias + (size_t)s * OUT_DIM;
  float bv[4];
#pragma unroll
  for (int fn = 0; fn < 4; ++fn) bv[fn] = bp[nt * 128 + wn + fn * 16 + fr];

  float* orow =
      out + ((size_t)batch * T_DIM + mt * 128 + wm) * OUT_DIM + nt * 128 + wn;
#pragma unroll
  for (int fm = 0; fm < 4; ++fm)
#pragma unroll
    for (int fn = 0; fn < 4; ++fn)
#pragma unroll
      for (int r = 0; r < 4; ++r)
        orow[(size_t)(fm * 16 + r0 + r) * OUT_DIM + fn * 16 + fr] =
            acc[fm][fn][r] + bv[fn];
}

// Emergency fallback if d_ws is too small: correct but slow.
__global__ __launch_bounds__(256) void naive_kernel(
    const float* __restrict__ x, const int* __restrict__ sid,
    const float* __restrict__ w, const float* __restrict__ bias,
    float* __restrict__ out) {
  __shared__ float lx[IN_DIM];
  size_t bt = blockIdx.x;
  int batch = (int)(bt / T_DIM);
  int s = sid[batch];
  int o = threadIdx.x;
  lx[o] = x[bt * IN_DIM + o];
  __syncthreads();
  const float* wp = w + (size_t)s * IN_DIM * OUT_DIM + o;
  float acc = bias[(size_t)s * OUT_DIM + o];
  for (int i = 0; i < IN_DIM; ++i) acc += lx[i] * wp[(size_t)i * OUT_DIM];
  out[bt * OUT_DIM + o] = acc;
}

extern "C" void kernel_launch(void* const* d_in, const int* in_sizes, int n_in,
                              void* d_out, int out_size, void* d_ws, size_t ws_size,
                              hipStream_t stream) {
  const float* x = (const float*)d_in[0];
  const int* sid = (const int*)d_in[1];
  const float* w = (const float*)d_in[2];
  const float* bias = (const float*)d_in[3];
  float* out = (float*)d_out;

  size_t need = (size_t)S_DIM * IN_DIM * OUT_DIM * sizeof(unsigned short);
  if (ws_size >= need) {
    unsigned short* wT = (unsigned short*)d_ws;
    wt_transpose<<<dim3(S_DIM * 16), dim3(256), 0, stream>>>(w, wT);
    subj_gemm<<<dim3(2048), dim3(256), 0, stream>>>(x, sid, wT, bias, out);
  } else {
    naive_kernel<<<dim3(B_DIM * T_DIM), dim3(256), 0, stream>>>(x, sid, w, bias, out);
  }
}